// Round 13
// baseline (596.519 us; speedup 1.0000x reference)
//
#include <hip/hip_runtime.h>

// Fused StyleGAN2 conv_downsample_2d, f32, register-FIR + SGPR-w GEMM,
// 2-deep register prefetch pipeline.
//   out[n,oc,oh,ow] = sum_c w[c,oc] * y[n,c,2oh,2ow]
//   y = separable FIR {1,3,3,1}/8 (vert) x {1,3,3,1}/8 (horiz), pad=1
//
// Design ledger (r1-r12):
//  - bf16 MFMA: precision-independent ~0.7 absmax on this op -> f32 VALU.
//  - NEVER pass __launch_bounds__ min-waves arg (r6/r8 spilled).
//  - v7 structure (r12): v-tile only in LDS, SGPR w, 0 bank conflicts, 412 us.
//    Remaining stall: prefetch->use distance was 1 iteration (~600 cyc) <
//    HBM latency (~900 cyc) -> per-chunk vmcnt stall at vwrite.
//  - This round: TWO register buffers (xrA/xrB), manually 2x-unrolled chunk
//    loop (static buffer naming, rule #20), issue chunk t+3 at iter t ->
//    distance ~2 GEMM phases > HBM latency. Register diet to stay <=64 VGPR:
//    off[10] -> uniform rowoff (SGPR) + clamped per-lane col + cndmask.
//
// Block 512 thr = 8 waves. Tile: 256 oc x (4 oh x 16 ow). Wave = 32-oc strip,
// lane = one of 64 sp. 16 chunks of 8 ch; wave wv stages channel c0+wv:
// lanes 0..33 own patch columns (10 rows), vertical FIR in registers.

#define VS 35   // v_s col pitch (odd -> 2-way max on GEMM reads; measured 0 conflicts)

__global__ __launch_bounds__(512)
void fused_downconv_v8(const float* __restrict__ x, const float* __restrict__ w,
                       float* __restrict__ out) {
    __shared__ __align__(16) float v_s[2 * 8 * 4 * VS];   // 8960 B

    const int tid  = threadIdx.x;
    const int lane = tid & 63;
    const int wv   = tid >> 6;   // wave id: staged channel offset, oc strip
    const int oc0  = __builtin_amdgcn_readfirstlane((tid >> 6) << 5);

    const int ow0 = blockIdx.x * 16;
    const int oh0 = blockIdx.y * 4;
    const int n   = blockIdx.z;

    const int rbase = 2 * oh0 - 1;
    const int cbase = 2 * ow0 - 1;

    // ---- staging map: lane<34 owns col cbase+lane, rows rbase..rbase+9 ----
    // Loads are always address-safe (clamped); OOB values zeroed via mask.
    const int gc   = cbase + lane;
    const bool cok = (lane < 34) && ((unsigned)gc < 512u);
    const int gcc  = min(max(gc, 0), 511);
    int rowoff[10];            // wave-uniform -> SGPRs
    unsigned rmask = 0;
    #pragma unroll
    for (int k = 0; k < 10; k++) {
        int gr = rbase + k;
        rowoff[k] = min(max(gr, 0), 511) * 512;
        if ((unsigned)gr < 512u) rmask |= (1u << k);
    }
    const unsigned lmask = cok ? rmask : 0u;

    const int owl = lane & 15;   // GEMM spatial mapping
    const int ohl = lane >> 4;

    float xrA[10], xrB[10];
    float acc[32];
    #pragma unroll
    for (int i = 0; i < 32; i++) acc[i] = 0.f;

    auto prefetch = [&](float (&xr)[10], int c0) {
        const float* xb = x + ((size_t)(n * 128 + c0 + wv)) * 262144 + gcc;
        #pragma unroll
        for (int k = 0; k < 10; k++) {
            float v = xb[rowoff[k]];
            xr[k] = ((lmask >> k) & 1u) ? v : 0.f;
        }
    };
    auto vwrite = [&](float (&xr)[10], int buf) {
        if (lane < 34) {
            #pragma unroll
            for (int o = 0; o < 4; o++) {
                float v = 0.125f * (xr[2 * o] + xr[2 * o + 3])
                        + 0.375f * (xr[2 * o + 1] + xr[2 * o + 2]);
                v_s[((buf * 8 + wv) * 4 + o) * VS + lane] = v;
            }
        }
    };
    auto gemm = [&](int buf, int ch) {
        #pragma unroll
        for (int cc = 0; cc < 8; cc++) {
            const float* vp = &v_s[((buf * 8 + cc) * 4 + ohl) * VS + 2 * owl];
            float v0 = vp[0], v1 = vp[1], v2 = vp[2], v3 = vp[3];
            float y = 0.125f * (v0 + v3) + 0.375f * (v1 + v2);
            const float* wrow = w + ((ch * 8 + cc) << 8) + oc0;  // wave-uniform -> s_load
            #pragma unroll
            for (int i = 0; i < 32; i++)
                acc[i] = fmaf(wrow[i], y, acc[i]);
        }
    };

    // ---- prologue: buf0 <- chunk0; A <- chunk1; B <- chunk2 ----
    prefetch(xrA, 0);
    vwrite(xrA, 0);
    prefetch(xrA, 8);
    prefetch(xrB, 16);
    __syncthreads();

    // Invariant entering tt: xrA = chunk 2tt+1, xrB = chunk 2tt+2,
    // buf(t&1) holds chunk t for the upcoming gemm.
    for (int tt = 0; tt < 8; tt++) {
        const int t0 = 2 * tt, t1 = 2 * tt + 1;
        // ---- even step: chunk t0 ----
        vwrite(xrA, 1);                           // chunk t0+1 (odd) -> buf1
        if (tt < 7) prefetch(xrA, 8 * (t0 + 3));  // chunk t0+3 -> A
        gemm(0, t0);
        __syncthreads();
        // ---- odd step: chunk t1 ----
        if (tt < 7) vwrite(xrB, 0);               // chunk t1+1 (even) -> buf0
        if (tt < 6) prefetch(xrB, 8 * (t1 + 3));  // chunk t1+3 -> B
        gemm(1, t1);
        __syncthreads();
    }

    // ---- epilogue: oc = oc0+i, oh = oh0+ohl, ow = ow0+owl ----
    {
        size_t base = (((size_t)n * 256 + oc0) * 256 + (size_t)(oh0 + ohl)) * 256
                      + ow0 + owl;
        #pragma unroll
        for (int i = 0; i < 32; i++)
            out[base + (size_t)i * 65536] = acc[i];
    }
}

extern "C" void kernel_launch(void* const* d_in, const int* in_sizes, int n_in,
                              void* d_out, int out_size, void* d_ws, size_t ws_size,
                              hipStream_t stream) {
    const float* x = (const float*)d_in[0];
    const float* w = (const float*)d_in[1];
    float* out = (float*)d_out;

    dim3 grid(16, 64, 4);   // ow-tiles(16 wide), oh-tiles(4 tall), n
    dim3 block(512);
    hipLaunchKernelGGL(fused_downconv_v8, grid, block, 0, stream, x, w, out);
}

// Round 14
// 423.763 us; speedup vs baseline: 1.4077x; 1.4077x over previous
//
#include <hip/hip_runtime.h>

// Fused StyleGAN2 conv_downsample_2d, f32, register-FIR + SGPR-w GEMM.
// r12 structure + ONE change: GEMM LDS reads 4x ds_read_b32 -> 2x float2
// (ds_read2_b64), VS 35 -> 36 for 8B alignment.
//   out[n,oc,oh,ow] = sum_c w[c,oc] * y[n,c,2oh,2ow]
//   y = separable FIR {1,3,3,1}/8 (vert) x {1,3,3,1}/8 (horiz), pad=1
//
// Design ledger (r1-r13):
//  - bf16 MFMA: precision-independent ~0.7 absmax on this op -> f32 VALU.
//  - NEVER pass __launch_bounds__ min-waves arg (r6/r8 spilled).
//  - r13: manual 2-deep/2x-unrolled pipeline DOUBLED issued VALU -> 597 us.
//    Compiler schedules the simple 1-deep loop better. Keep r12 skeleton.
//  - r12 analysis: LDS pipe (32 scalar ds_read_b32/thread/chunk in GEMM)
//    co-critical with VALU (~170 us each). This round: paired b64 reads
//    -> 8 LDS instr/thread/chunk.
//
// Block 512 thr = 8 waves. Tile: 256 oc x (4 oh x 16 ow). Wave = 32-oc strip,
// lane = one of 64 sp. 16 chunks of 8 ch; wave wv stages channel c0+wv:
// lanes 0..33 own patch columns (10 rows x 34 cols), vertical FIR in regs.

#define VS 36   // v_s col pitch (even -> 8B-aligned pair reads; 2-way banks max)

__global__ __launch_bounds__(512)
void fused_downconv_v9(const float* __restrict__ x, const float* __restrict__ w,
                       float* __restrict__ out) {
    __shared__ __align__(16) float v_s[2 * 8 * 4 * VS];   // 9216 B

    const int tid  = threadIdx.x;
    const int lane = tid & 63;
    const int wv   = tid >> 6;   // wave id: staged channel offset, oc strip
    const int oc0  = __builtin_amdgcn_readfirstlane((tid >> 6) << 5);

    const int ow0 = blockIdx.x * 16;
    const int oh0 = blockIdx.y * 4;
    const int n   = blockIdx.z;

    const int rbase = 2 * oh0 - 1;
    const int cbase = 2 * ow0 - 1;

    // ---- staging map: lane<34 owns col cbase+lane, rows rbase..rbase+9 ----
    int off[10];
    unsigned ldmask = 0;
    {
        int gc = cbase + lane;
        bool cok = (lane < 34) && ((unsigned)gc < 512u);
        #pragma unroll
        for (int k = 0; k < 10; k++) {
            int gr = rbase + k;
            bool ok = cok && ((unsigned)gr < 512u);
            off[k] = ok ? (gr * 512 + gc) : 0;
            if (ok) ldmask |= 1u << k;
        }
    }

    const int owl = lane & 15;   // GEMM spatial mapping
    const int ohl = lane >> 4;

    float xr[10];
    float acc[32];
    #pragma unroll
    for (int i = 0; i < 32; i++) acc[i] = 0.f;

    auto prefetch = [&](int c0) {
        const float* xb = x + ((size_t)(n * 128 + c0 + wv)) * 262144;
        #pragma unroll
        for (int k = 0; k < 10; k++)
            xr[k] = ((ldmask >> k) & 1u) ? xb[off[k]] : 0.f;
    };
    auto vwrite = [&](int buf) {
        if (lane < 34) {
            #pragma unroll
            for (int o = 0; o < 4; o++) {
                float v = 0.125f * (xr[2 * o] + xr[2 * o + 3])
                        + 0.375f * (xr[2 * o + 1] + xr[2 * o + 2]);
                v_s[((buf * 8 + wv) * 4 + o) * VS + lane] = v;
            }
        }
    };

    prefetch(0);
    vwrite(0);
    prefetch(8);
    __syncthreads();

    for (int t = 0; t < 16; t++) {
        const int buf = t & 1;
        if (t < 15) {
            vwrite(buf ^ 1);                  // chunk t+1 -> other buffer
            if (t < 14) prefetch((t + 2) * 8); // issue loads for chunk t+2
        }
        // ---- GEMM over the 8 channels of chunk t ----
        #pragma unroll
        for (int cc = 0; cc < 8; cc++) {
            const float* vp = &v_s[((buf * 8 + cc) * 4 + ohl) * VS + 2 * owl];
            float2 p0 = *(const float2*)&vp[0];   // 8B-aligned (VS even)
            float2 p1 = *(const float2*)&vp[2];   // merges into ds_read2_b64
            float y = 0.125f * (p0.x + p1.y) + 0.375f * (p0.y + p1.x);
            const float* wrow = w + ((t * 8 + cc) << 8) + oc0;  // wave-uniform -> s_load
            #pragma unroll
            for (int i = 0; i < 32; i++)
                acc[i] = fmaf(wrow[i], y, acc[i]);
        }
        __syncthreads();   // v-writes(t+1) visible; GEMM(t) reads drained
    }

    // ---- epilogue: oc = oc0+i, oh = oh0+ohl, ow = ow0+owl ----
    {
        size_t base = (((size_t)n * 256 + oc0) * 256 + (size_t)(oh0 + ohl)) * 256
                      + ow0 + owl;
        #pragma unroll
        for (int i = 0; i < 32; i++)
            out[base + (size_t)i * 65536] = acc[i];
    }
}

extern "C" void kernel_launch(void* const* d_in, const int* in_sizes, int n_in,
                              void* d_out, int out_size, void* d_ws, size_t ws_size,
                              hipStream_t stream) {
    const float* x = (const float*)d_in[0];
    const float* w = (const float*)d_in[1];
    float* out = (float*)d_out;

    dim3 grid(16, 64, 4);   // ow-tiles(16 wide), oh-tiles(4 tall), n
    dim3 block(512);
    hipLaunchKernelGGL(fused_downconv_v9, grid, block, 0, stream, x, w, out);
}